// Round 5
// baseline (56.162 us; speedup 1.0000x reference)
//
#include <hip/hip_runtime.h>

// ball_query(radius=3.4, nsample=5) — ONE WAVE PER QUERY, peeled first iter.
// B=8, N=4096, D=3. Output [B, N, 5] int32.
//
// Round 5: with hit-prob ~0.88, >=5 hits land in the first 64 points for
// ~99% of queries — so iteration 1 is peeled into a straight-line path
// (load -> ballot -> rank -> store -> exit) with no loop-carried state.
// The rare outlier tail (hit-prob down to ~0.06 for ||q||~4.9) runs a
// wave-uniform cold loop. block=1024 cuts workgroups 8192 -> 2048.
//
// d2 must match the numpy reference at the r2 boundary:
//   d2 = (sq_q + sq_k) - 2*dot, sq/dot separately-rounded f32 (no fma) —
//   file-scope fp contract(off). Self-distance is exactly 0 with this
//   expression, so every query has >=1 hit (first-hit fill always valid).

#pragma clang fp contract(off)

#define BQ_N 4096
#define BQ_B 8
#define BQ_NS 5

__global__ __launch_bounds__(1024) void ball_query_kernel(
    const float* __restrict__ x, int* __restrict__ out, float r2) {
  const int wid = (blockIdx.x * 1024 + threadIdx.x) >> 6;  // global wave = query
  const int lane = threadIdx.x & 63;
  const int b = wid >> 12;         // / 4096
  const int q = wid & (BQ_N - 1);  // % 4096

  const float* xb = x + (size_t)b * BQ_N * 3;

  // Query coords (uniform-address broadcast) and first 64 candidate points:
  // all loads independent -> one waitcnt round.
  const float qx = xb[q * 3 + 0];
  const float qy = xb[q * 3 + 1];
  const float qz = xb[q * 3 + 2];
  const float kx0 = xb[lane * 3 + 0];
  const float ky0 = xb[lane * 3 + 1];
  const float kz0 = xb[lane * 3 + 2];

  const float sq_q = (qx * qx + qy * qy) + qz * qz;
  const float sqk0 = (kx0 * kx0 + ky0 * ky0) + kz0 * kz0;
  const float dot0 = (qx * kx0 + qy * ky0) + qz * kz0;
  const float d20 = (sq_q + sqk0) - 2.0f * dot0;

  const int base = wid * BQ_NS;
  const unsigned long long below = ((unsigned long long)1 << lane) - 1ull;

  const unsigned long long m1 = __ballot(d20 < r2);
  if (d20 < r2) {
    const int rank = __popcll(m1 & below);
    if (rank < BQ_NS) out[base + rank] = lane;
  }
  int cnt = __popcll(m1);

  if (cnt < BQ_NS) {  // wave-uniform cold path (~1% of queries)
    int first = (m1 != 0ull) ? (__ffsll((long long)m1) - 1) : -1;
    for (int k0 = 64; k0 < BQ_N && cnt < BQ_NS; k0 += 64) {
      const int k = k0 + lane;
      const float kx = xb[k * 3 + 0];
      const float ky = xb[k * 3 + 1];
      const float kz = xb[k * 3 + 2];
      const float sqk = (kx * kx + ky * ky) + kz * kz;
      const float dot = (qx * kx + qy * ky) + qz * kz;
      const float d2 = (sq_q + sqk) - 2.0f * dot;
      const bool h = d2 < r2;
      const unsigned long long m = __ballot(h);
      if (h) {
        const int rank = cnt + __popcll(m & below);
        if (rank < BQ_NS) out[base + rank] = k;
      }
      if (first < 0 && m != 0ull) first = k0 + __ffsll((long long)m) - 1;
      cnt += __popcll(m);
    }
    // Unfilled slots hold the FIRST found index (cnt >= 1 always: self-hit).
    if (lane == 0 && cnt < BQ_NS) {
      for (int j = (cnt < 1 ? 1 : cnt); j < BQ_NS; ++j) out[base + j] = first;
    }
  }
}

extern "C" void kernel_launch(void* const* d_in, const int* in_sizes, int n_in,
                              void* d_out, int out_size, void* d_ws, size_t ws_size,
                              hipStream_t stream) {
  const float* x = (const float*)d_in[0];
  int* out = (int*)d_out;
  const float r2 = 3.4f * 3.4f;  // 11.56

  const int total_waves = BQ_B * BQ_N;  // 32768 queries, 1 wave each
  const int block = 1024;               // 16 waves/block
  const int grid = total_waves / 16;    // 2048 blocks
  ball_query_kernel<<<grid, block, 0, stream>>>(x, out, r2);
}

// Round 6
// 55.113 us; speedup vs baseline: 1.0190x; 1.0190x over previous
//
#include <hip/hip_runtime.h>

// ball_query(radius=3.4, nsample=5) — 16 LANES PER QUERY (4 queries/wave).
// B=8, N=4096, D=3. Output [B, N, 5] int32.
//
// Round 6: one-wave-per-query tested 64 points/query but only ~6 are needed
// (hit prob ~0.88) -> ~90% wasted lane-work. Now each 16-lane group handles
// one query: P(>=5 hits in first 16 points) ~ 0.999 for typical queries.
// Wave count drops 32768 -> 8192; grid 2048 -> 512 blocks. The 4 queries in
// a wave are consecutive (same batch; 4096 % 4 == 0), so candidate loads are
// the same 16 points replicated across groups (L1 broadcast). Rare cold
// groups loop 16 points/step under a wave-wide __any exit.
//
// d2 must match the numpy reference at the r2 boundary:
//   d2 = (sq_q + sq_k) - 2*dot, sq/dot separately-rounded f32 (no fma) —
//   file-scope fp contract(off). Self-distance is exactly 0 with this
//   expression, so every query has >=1 hit (first-hit fill always valid).

#pragma clang fp contract(off)

#define BQ_N 4096
#define BQ_B 8
#define BQ_NS 5

__global__ __launch_bounds__(1024) void ball_query_kernel(
    const float* __restrict__ x, int* __restrict__ out, float r2) {
  const int wid = (blockIdx.x * 1024 + threadIdx.x) >> 6;  // global wave
  const int lane = threadIdx.x & 63;
  const int group = lane >> 4;   // 0..3 — which query this lane serves
  const int sub = lane & 15;     // 0..15 — candidate offset within chunk

  const int qidx = wid * 4 + group;   // 4 consecutive queries per wave
  const int b = qidx >> 12;           // / 4096 (wave-uniform: qidx aligned 4)
  const int q = qidx & (BQ_N - 1);    // % 4096

  const float* xb = x + (size_t)b * BQ_N * 3;

  // Query coords + first 16 candidates (replicated across groups).
  const float qx = xb[q * 3 + 0];
  const float qy = xb[q * 3 + 1];
  const float qz = xb[q * 3 + 2];
  const float kx0 = xb[sub * 3 + 0];
  const float ky0 = xb[sub * 3 + 1];
  const float kz0 = xb[sub * 3 + 2];

  const float sq_q = (qx * qx + qy * qy) + qz * qz;
  const float sqk0 = (kx0 * kx0 + ky0 * ky0) + kz0 * kz0;
  const float dot0 = (qx * kx0 + qy * ky0) + qz * kz0;
  const float d20 = (sq_q + sqk0) - 2.0f * dot0;

  const int base = qidx * BQ_NS;
  const unsigned sublow = (1u << sub) - 1u;  // bits below sub within group

  const unsigned long long m1 = __ballot(d20 < r2);
  const unsigned mg1 = (unsigned)(m1 >> (group * 16)) & 0xFFFFu;
  if (d20 < r2) {
    const int rank = __popc(mg1 & sublow);
    if (rank < BQ_NS) out[base + rank] = sub;
  }
  int cnt = __popc(mg1);  // group-uniform

  if (__any(cnt < BQ_NS)) {  // rare cold path (~4% of waves)
    int first = (mg1 != 0u) ? (__ffs(mg1) - 1) : -1;
    for (int k0 = 16; k0 < BQ_N && __any(cnt < BQ_NS); k0 += 16) {
      const int k = k0 + sub;
      const float kx = xb[k * 3 + 0];
      const float ky = xb[k * 3 + 1];
      const float kz = xb[k * 3 + 2];
      const float sqk = (kx * kx + ky * ky) + kz * kz;
      const float dot = (qx * kx + qy * ky) + qz * kz;
      const float d2 = (sq_q + sqk) - 2.0f * dot;
      const bool h = (d2 < r2) && (cnt < BQ_NS + 16);  // cheap overflow guard
      const unsigned long long m = __ballot(d2 < r2);
      const unsigned mg = (unsigned)(m >> (group * 16)) & 0xFFFFu;
      if (h && cnt < BQ_NS) {
        const int rank = cnt + __popc(mg & sublow);
        if (rank < BQ_NS) out[base + rank] = k;
      }
      if (first < 0 && mg != 0u) first = k0 + __ffs(mg) - 1;
      if (cnt < BQ_NS) cnt += __popc(mg);
    }
    // Unfilled slots hold the FIRST found index (cnt >= 1 always: self-hit).
    if (sub == 0 && cnt < BQ_NS) {
      for (int j = (cnt < 1 ? 1 : cnt); j < BQ_NS; ++j) out[base + j] = first;
    }
  }
}

extern "C" void kernel_launch(void* const* d_in, const int* in_sizes, int n_in,
                              void* d_out, int out_size, void* d_ws, size_t ws_size,
                              hipStream_t stream) {
  const float* x = (const float*)d_in[0];
  int* out = (int*)d_out;
  const float r2 = 3.4f * 3.4f;  // 11.56

  const int total_waves = (BQ_B * BQ_N) / 4;  // 4 queries per wave -> 8192
  const int block = 1024;                     // 16 waves/block
  const int grid = total_waves / 16;          // 512 blocks
  ball_query_kernel<<<grid, block, 0, stream>>>(x, out, r2);
}